// Round 16
// baseline (103.603 us; speedup 1.0000x reference)
//
#include <hip/hip_runtime.h>
#include <hip/hip_bf16.h>

// AgreementRouting, 4-kernel full-machine plan (R15 base) + l-major u16
// layout (vectorizable 20B/lane loads) + 4-deep prefetch + F merged into I3.
// B=128, IC=1152, OC=10, D=16, 3 iters, f32 in/out.
//
// A  (1024x256): zero s_red[1..3]+cnt; stream f32 u ONCE (NT) -> u16 (l-major:
//     lane l owns dwords [l*5..l*5+4] per slice -> contiguous, LSV merges to
//     dwordx4+dword) + s0 partials.
// I<T>(1024x256): prologue T==1: v=squash(reduce8 s0); T>1: v=v_acc[T-1]+
//     squash(s_red[T-1]). part0 stores v_acc[T]. 4-deep prefetched 9-slice
//     loop (all 4 initial loads issued BEFORE prologue). atomicAdd row into
//     s_red[T]. I3: last-arriving block per b (cnt[b] ACQ_REL) re-reads
//     s_red[3] with agent loads, squashes -> out (F kernel eliminated).
// Logits: bb_T = b_in + <u, sum_{t<T} v_t> (linearity, R2-proven).
//
// Lessons enforced: no in-kernel cross-block barrier/polling (R12: ~200us);
// no register-resident u (R11: spill); PARTS_=8 (R14: 18-way regressed).
//
// Lane scheme per 16-lane group (slice = 10x16 f32): l=tid&15, h=l>>3.
// Lane owns (j=2k+h, d=2(l&7)..2(l&7)+1), k=0..4 == float offset 32k+2l.
// Cross-lane in hot loops: all DPP (VALU pipe), R6-proven.

#define B_     128
#define IC_    1152
#define OC_    10
#define ROW_   160
#define WPS_   80      // bf16 dwords per slice
#define PARTS_ 8
#define SPB_   144     // slices per part
#define UPB_   9       // slices per 16-lane group
#define SOUT_  20480   // B_*ROW_

typedef float v2f __attribute__((ext_vector_type(2)));

__device__ __forceinline__ float bf_lo(uint32_t w) { return __uint_as_float(w << 16); }
__device__ __forceinline__ float bf_hi(uint32_t w) { return __uint_as_float(w & 0xffff0000u); }

template<int CTRL>
__device__ __forceinline__ float dppf(float x) {
    return __int_as_float(__builtin_amdgcn_update_dpp(
        0, __float_as_int(x), CTRL, 0xF, 0xF, true));
}
__device__ __forceinline__ float dpp_sum8(float x) {
    x += dppf<0xB1>(x);    // quad_perm [1,0,3,2]  (xor1)
    x += dppf<0x4E>(x);    // quad_perm [2,3,0,1]  (xor2)
    x += dppf<0x141>(x);   // row_half_mirror      (cross-quad within 8)
    return x;
}
__device__ __forceinline__ float softmax10(float own[5]) {
    float m = own[0];
#pragma unroll
    for (int k = 1; k < 5; ++k) m = fmaxf(m, own[k]);
    m = fmaxf(m, dppf<0x128>(m));          // row_ror:8 == xor8 within 16
    float sum = 0.f;
#pragma unroll
    for (int k = 0; k < 5; ++k) { own[k] = __expf(own[k] - m); sum += own[k]; }
    sum += dppf<0x128>(sum);
    return 1.f / sum;
}
__device__ __forceinline__ float squash_row(float x) {
    float sq = x * x;
    sq += __shfl_xor(sq, 1, 16);
    sq += __shfl_xor(sq, 2, 16);
    sq += __shfl_xor(sq, 4, 16);
    sq += __shfl_xor(sq, 8, 16);
    return (sq / (1.f + sq)) * x * rsqrtf(sq + 1e-8f);
}
__device__ __forceinline__ float agent_loadf(const float* p) {
    return __hip_atomic_load(p, __ATOMIC_RELAXED, __HIP_MEMORY_SCOPE_AGENT);
}

// ---------------- Kernel A ----------------
__global__ __launch_bounds__(256) void a_kernel(
    const float* __restrict__ u, const float* __restrict__ b_in,
    uint32_t* __restrict__ u16, float* __restrict__ s0_part,
    float* __restrict__ s_red)   // s_red[1..3] + cnt[B_], zeroed here
{
    const int bid = blockIdx.x, tid = threadIdx.x;
    const int l = tid & 15, h = l >> 3, g = tid >> 4;
    const int b = bid >> 3, part = bid & 7;
    const int wave = tid >> 6, lane = tid & 63;

    const int gidx = bid * 256 + tid;
    if (gidx < 3 * SOUT_ + B_) s_red[gidx] = 0.f;   // includes cnt as 0-bits

    __shared__ float red[4][ROW_];
    __shared__ float b_lds[SPB_ * OC_];

#pragma unroll
    for (int it = 0; it < 6; ++it) {
        int idx = it * 256 + tid;
        if (idx < SPB_ * OC_) b_lds[idx] = b_in[part * SPB_ * OC_ + idx];
    }
    __syncthreads();

    float2 sc[5];
#pragma unroll
    for (int k = 0; k < 5; ++k) { sc[k].x = 0.f; sc[k].y = 0.f; }
#pragma unroll
    for (int uu = 0; uu < UPB_; ++uu) {
        const int su = uu * 16 + g;
        const int i  = part * SPB_ + su;
        const v2f* up = (const v2f*)(u + (size_t)(b * IC_ + i) * ROW_ + 2 * l);
        v2f uv[5];
#pragma unroll
        for (int k = 0; k < 5; ++k) uv[k] = __builtin_nontemporal_load(up + 16 * k);

        // l-major u16: lane l owns dwords [l*5 .. l*5+4] (contiguous 20B)
        uint32_t* wp = u16 + (size_t)(b * IC_ + i) * WPS_ + l * 5;
#pragma unroll
        for (int k = 0; k < 5; ++k) {
            __hip_bfloat16 bx = __float2bfloat16(uv[k].x);
            __hip_bfloat16 by = __float2bfloat16(uv[k].y);
            wp[k] = ((uint32_t)(*(const uint16_t*)&by) << 16) |
                     (uint32_t)(*(const uint16_t*)&bx);
        }
        float own[5];
#pragma unroll
        for (int k = 0; k < 5; ++k) own[k] = b_lds[su * OC_ + 2 * k + h];
        const float inv = softmax10(own);
#pragma unroll
        for (int k = 0; k < 5; ++k) {
            float c = own[k] * inv;
            sc[k].x += c * uv[k].x; sc[k].y += c * uv[k].y;
        }
    }
#pragma unroll
    for (int k = 0; k < 5; ++k) {
        sc[k].x += __shfl_xor(sc[k].x, 16); sc[k].y += __shfl_xor(sc[k].y, 16);
        sc[k].x += __shfl_xor(sc[k].x, 32); sc[k].y += __shfl_xor(sc[k].y, 32);
    }
    if (lane < 16) {
#pragma unroll
        for (int k = 0; k < 5; ++k)
            *(float2*)&red[wave][32 * k + 2 * l] = sc[k];
    }
    __syncthreads();
    if (tid < ROW_) {
        float t = red[0][tid] + red[1][tid] + red[2][tid] + red[3][tid];
        s0_part[(size_t)(b * PARTS_ + part) * ROW_ + tid] = t;
    }
}

// ---------------- Kernel I<T> ----------------
template<int T>
__global__ __launch_bounds__(256) void i_kernel(
    const uint32_t* __restrict__ u16, const float* __restrict__ b_in,
    const float* __restrict__ s0_part, const float* __restrict__ s_red_prev,
    const float* __restrict__ v_in, float* __restrict__ v_out,
    float* __restrict__ s_out, uint32_t* __restrict__ cnt,
    float* __restrict__ out)
{
    const int bid = blockIdx.x, tid = threadIdx.x;
    const int l = tid & 15, h = l >> 3, g = tid >> 4;
    const int b = bid >> 3, part = bid & 7;
    const int wave = tid >> 6, lane = tid & 63;

    __shared__ float red[4][ROW_];
    __shared__ float v_lds[ROW_];
    __shared__ float b_lds[SPB_ * OC_];

    // per-lane slice base (l-major layout): slice uu at +uu*16*WPS_ dwords
    const uint32_t* ubase = u16 + (size_t)(b * IC_ + part * SPB_ + g) * WPS_ + l * 5;

#define B_LOAD(UW, uu) do {                                                 \
        const uint32_t* wp_ = ubase + (size_t)(uu) * 16 * WPS_;             \
        _Pragma("unroll")                                                   \
        for (int k = 0; k < 5; ++k) UW[k] = wp_[k];                         \
    } while (0)

    // 4-deep prefetch, first 4 issued BEFORE the prologue
    uint32_t uwA[5], uwB[5], uwC[5], uwD[5];
    B_LOAD(uwA, 0);
    B_LOAD(uwB, 1);
    B_LOAD(uwC, 2);
    B_LOAD(uwD, 3);

#pragma unroll
    for (int it = 0; it < 6; ++it) {
        int idx = it * 256 + tid;
        if (idx < SPB_ * OC_) b_lds[idx] = b_in[part * SPB_ * OC_ + idx];
    }

    if (tid < ROW_) {
        float vsum;
        if (T == 1) {
            const float* sp = s0_part + (size_t)(b * PARTS_) * ROW_;
            float x = 0.f;
#pragma unroll
            for (int p = 0; p < PARTS_; ++p) x += sp[p * ROW_ + tid];
            vsum = squash_row(x);
        } else {
            vsum = v_in[b * ROW_ + tid] + squash_row(s_red_prev[b * ROW_ + tid]);
        }
        if (T < 3 && part == 0) v_out[b * ROW_ + tid] = vsum;
        v_lds[tid] = vsum;
    }
    __syncthreads();

    float2 vv[5];
#pragma unroll
    for (int k = 0; k < 5; ++k)
        vv[k] = *(const float2*)&v_lds[32 * k + 2 * l];

    float2 sc[5];
#pragma unroll
    for (int k = 0; k < 5; ++k) { sc[k].x = 0.f; sc[k].y = 0.f; }

#define B_COMP(UW, uu) do {                                                 \
        const int su_ = (uu) * 16 + g;                                      \
        float own[5];                                                       \
        _Pragma("unroll")                                                   \
        for (int k = 0; k < 5; ++k) own[k] = b_lds[su_ * OC_ + 2 * k + h];  \
        _Pragma("unroll")                                                   \
        for (int k = 0; k < 5; ++k) {                                       \
            float pd = bf_lo(UW[k]) * vv[k].x + bf_hi(UW[k]) * vv[k].y;     \
            own[k] += dpp_sum8(pd);                                         \
        }                                                                   \
        const float inv = softmax10(own);                                   \
        _Pragma("unroll")                                                   \
        for (int k = 0; k < 5; ++k) {                                       \
            float c = own[k] * inv;                                         \
            sc[k].x += c * bf_lo(UW[k]); sc[k].y += c * bf_hi(UW[k]);       \
        }                                                                   \
    } while (0)

    B_COMP(uwA, 0); B_LOAD(uwA, 4);
    B_COMP(uwB, 1); B_LOAD(uwB, 5);
    B_COMP(uwC, 2); B_LOAD(uwC, 6);
    B_COMP(uwD, 3); B_LOAD(uwD, 7);
    B_COMP(uwA, 4); B_LOAD(uwA, 8);
    B_COMP(uwB, 5);
    B_COMP(uwC, 6);
    B_COMP(uwD, 7);
    B_COMP(uwA, 8);
#undef B_LOAD
#undef B_COMP

#pragma unroll
    for (int k = 0; k < 5; ++k) {
        sc[k].x += __shfl_xor(sc[k].x, 16); sc[k].y += __shfl_xor(sc[k].y, 16);
        sc[k].x += __shfl_xor(sc[k].x, 32); sc[k].y += __shfl_xor(sc[k].y, 32);
    }
    if (lane < 16) {
#pragma unroll
        for (int k = 0; k < 5; ++k)
            *(float2*)&red[wave][32 * k + 2 * l] = sc[k];
    }
    __syncthreads();
    if (tid < ROW_) {
        float t = red[0][tid] + red[1][tid] + red[2][tid] + red[3][tid];
        atomicAdd(&s_out[b * ROW_ + tid], t);
    }

    if (T == 3) {
        // last-arriving block of this b reduces + squashes -> out
        __shared__ int is_last;
        __syncthreads();           // drains the atomicAdds (vmcnt) block-wide
        if (tid == 0) {
            __threadfence();
            uint32_t old = __hip_atomic_fetch_add(&cnt[b], 1u,
                              __ATOMIC_ACQ_REL, __HIP_MEMORY_SCOPE_AGENT);
            is_last = (old == PARTS_ - 1);
        }
        __syncthreads();
        if (is_last && tid < ROW_) {
            float x = agent_loadf(&s_out[b * ROW_ + tid]);
            out[b * ROW_ + tid] = squash_row(x);
        }
    }
}

extern "C" void kernel_launch(void* const* d_in, const int* in_sizes, int n_in,
                              void* d_out, int out_size, void* d_ws, size_t ws_size,
                              hipStream_t stream) {
    const float* u    = (const float*)d_in[0];
    const float* b_in = (const float*)d_in[1];
    float* out = (float*)d_out;

    float*    s0_part = (float*)d_ws;                          // B_*8*160 f32
    float*    s_red   = s0_part + (size_t)B_ * PARTS_ * ROW_;  // 3*SOUT_ + cnt
    uint32_t* cnt     = (uint32_t*)(s_red + 3 * SOUT_);        // B_ u32
    float*    v_acc   = (float*)(cnt + B_);                    // 2*SOUT_
    uint32_t* u16     = (uint32_t*)(v_acc + 2 * SOUT_);        // 47.2 MB

    const dim3 blk(256);
    const dim3 grid(B_ * PARTS_);      // 1024

    a_kernel<<<grid, blk, 0, stream>>>(u, b_in, u16, s0_part, s_red);
    i_kernel<1><<<grid, blk, 0, stream>>>(u16, b_in, s0_part, nullptr,
                                          nullptr, v_acc, s_red,
                                          nullptr, nullptr);
    i_kernel<2><<<grid, blk, 0, stream>>>(u16, b_in, s0_part, s_red,
                                          v_acc, v_acc + SOUT_, s_red + SOUT_,
                                          nullptr, nullptr);
    i_kernel<3><<<grid, blk, 0, stream>>>(u16, b_in, s0_part, s_red + SOUT_,
                                          v_acc + SOUT_, nullptr, s_red + 2 * SOUT_,
                                          cnt, out);
}